// Round 9
// baseline (209.271 us; speedup 1.0000x reference)
//
#include <hip/hip_runtime.h>

#define NSP 16384   // H*W
#define CCH 64
#define BATCH 32
#define SPLIT 16
#define CPB (CCH / SPLIT)   // 4 channels per block

// LDS tile: full-width strip. 34 used quads/row (136 cols: 128 + 8 halo), pad to 40.
#define LW 160              // words per LDS row (40 quads)
#define LH 40               // rows: 32 + 8 halo
#define LDSF (LW * LH)      // 6400 floats (25.6 KB, SINGLE buffer)
#define NQ (LDSF / 4)       // 1600 quads
#define NISS 7              // ceil(1600/256); 7th issue only tid<64

__device__ __forceinline__ void gload_lds16(const float* g, float* l) {
    __builtin_amdgcn_global_load_lds(
        (const __attribute__((address_space(1))) void*)g,
        (__attribute__((address_space(3))) void*)l,
        16, 0, 0);
}

// quad-column swizzle: involution, spreads W=8 read pattern across bank groups
__device__ __forceinline__ int swq(int q) { return q ^ ((q >> 3) & 7); }

__device__ __forceinline__ unsigned short f2bf(float f) {   // RNE
    unsigned u = __float_as_uint(f);
    u += 0x7fffu + ((u >> 16) & 1u);
    return (unsigned short)(u >> 16);
}
__device__ __forceinline__ float bflo(unsigned u) { return __uint_as_float(u << 16); }
__device__ __forceinline__ float bfhi(unsigned u) { return __uint_as_float(u & 0xffff0000u); }
__device__ __forceinline__ float bfu(unsigned short h) {
    return __uint_as_float((unsigned)h << 16);
}

// ---------------- K1: PURE depthwise 9x9 conv, occupancy-optimized ----------------
// Tiles: 4 per plane (128 cols x 32 rows). Threads 256 = 16x16; thread owns
// 8 cols x 2 rows. SINGLE LDS buffer (25.6 KB) -> 6 blocks/CU, 24 waves/CU.
// SPLIT=16 -> 2048 blocks. Inter-block TLP replaces intra-block prefetch:
// while this block waits on its stage, ~4 other blocks on the CU compute.
template<int YBF>
__global__ __launch_bounds__(256, 6) void conv_kernel(
    const float* __restrict__ x, const float* __restrict__ wdw,
    const float* __restrict__ bdw, const float* __restrict__ zpad,
    float* __restrict__ yf, unsigned short* __restrict__ yb)
{
    const int tile = blockIdx.x;            // 0..3: 32-row strips
    const int b    = blockIdx.y;
    const int sp   = blockIdx.z;            // channel split 0..15
    const int tile_ry = tile * 32;
    const int tid = threadIdx.x;
    const int tx = tid & 15, ty = tid >> 4;
    const int c0 = tx * 8, r0 = ty * 2;     // 8 cols x 2 rows per thread
    const int cbase = sp * CPB;

    __shared__ float buf[LDSF];

    // staging geometry: LDS quad Q holds global quad swq(Q%40) of row Q/40
    int soff[NISS]; unsigned okm = 0;
    #pragma unroll
    for (int r = 0; r < NISS; ++r) {
        int q = tid + 256 * r;
        int lrow = q / 40, qcl = q - lrow * 40;
        int gq = swq(qcl);                  // global quad col (0 -> col -4)
        int gr = tile_ry - 4 + lrow;
        int gc = gq * 4 - 4;
        soff[r] = gr * 128 + gc;
        if (q < NQ && (unsigned)gr < 128u && gq >= 1 && gq <= 32) okm |= 1u << r;
    }

    // per-thread swizzled read base offsets (words), one per 16B column chunk
    int rb[4];
    #pragma unroll
    for (int j = 0; j < 4; ++j) rb[j] = r0 * LW + swq(2 * tx + j) * 4;

    const float* xb = x + (size_t)b * CCH * NSP;

#define STAGE(cc) do {                                                    \
        const float* plane_ = xb + (size_t)(cc) * NSP;                    \
        _Pragma("unroll")                                                 \
        for (int r_ = 0; r_ < NISS; ++r_) {                               \
            int q_ = tid + 256 * r_;                                      \
            if (q_ < NQ) {                                                \
                const float* g_ = ((okm >> r_) & 1u) ? plane_ + soff[r_]  \
                                                     : zpad;              \
                gload_lds16(g_, &buf[4 * q_]);                            \
            }                                                             \
        }                                                                 \
    } while (0)

    for (int k = 0; k < CPB; ++k) {
        const int c = cbase + k;
        STAGE(c);
        __syncthreads();                    // drains vmcnt: stage complete

        const float* wc = wdw + c * 81;     // uniform -> s_loads
        float acc[2][8] = {};
        #pragma unroll
        for (int ir = 0; ir < 10; ++ir) {
            float4 f0 = *(const float4*)(buf + rb[0] + ir * LW);
            float4 f1 = *(const float4*)(buf + rb[1] + ir * LW);
            float4 f2 = *(const float4*)(buf + rb[2] + ir * LW);
            float4 f3 = *(const float4*)(buf + rb[3] + ir * LW);
            float v[16] = {f0.x, f0.y, f0.z, f0.w, f1.x, f1.y, f1.z, f1.w,
                           f2.x, f2.y, f2.z, f2.w, f3.x, f3.y, f3.z, f3.w};
            #pragma unroll
            for (int o = 0; o < 2; ++o) {
                int tv = ir - o;
                if (tv >= 0 && tv <= 8) {
                    #pragma unroll
                    for (int kx = 0; kx < 9; ++kx) {
                        float w = wc[tv * 9 + kx];
                        #pragma unroll
                        for (int q = 0; q < 8; ++q) acc[o][q] += w * v[kx + q];
                    }
                }
            }
        }

        const float bias = bdw[c];
        const size_t ybase = (size_t)(b * CCH + c) * NSP + (tile_ry + r0) * 128 + c0;
        #pragma unroll
        for (int o = 0; o < 2; ++o) {
            float yv[8];
            #pragma unroll
            for (int q = 0; q < 8; ++q) yv[q] = acc[o][q] + bias;
            if (YBF) {
                uint4 s;
                s.x = (unsigned)f2bf(yv[0]) | ((unsigned)f2bf(yv[1]) << 16);
                s.y = (unsigned)f2bf(yv[2]) | ((unsigned)f2bf(yv[3]) << 16);
                s.z = (unsigned)f2bf(yv[4]) | ((unsigned)f2bf(yv[5]) << 16);
                s.w = (unsigned)f2bf(yv[6]) | ((unsigned)f2bf(yv[7]) << 16);
                *(uint4*)(yb + ybase + o * 128) = s;
            } else {
                *(float4*)(yf + ybase + o * 128) =
                    make_float4(yv[0], yv[1], yv[2], yv[3]);
                *(float4*)(yf + ybase + o * 128 + 4) =
                    make_float4(yv[4], yv[5], yv[6], yv[7]);
            }
        }
        __syncthreads();                    // all reads done: buf reusable
    }
#undef STAGE
}

// ---------------- K2: fused dots + sums, t computed on the fly --------------------
// t_x(p) = sum_j w1d[j] x[j,p] is POINTWISE in p: no materialized t planes.
// Grid: 1024 blocks = 32 b x 32 pb. Block handles 2 chunks of 256 pixels.
// Wave wv owns channels [16wv,16wv+16): 16 accumulators x 4 quantities.
// Output: dparts[4][32pb][32b][64c] partials, summed by att_kernel. No atomics.
template<int YBF>
__global__ __launch_bounds__(256) void dot_kernel(
    const float* __restrict__ x, const float* __restrict__ yf,
    const unsigned short* __restrict__ yb, const float* __restrict__ w1d,
    float* __restrict__ dparts)
{
    const int b    = blockIdx.x >> 5;
    const int pb   = blockIdx.x & 31;
    const int lane = threadIdx.x & 63;
    const int wv   = threadIdx.x >> 6;
    const int ibase = wv * 16;
    const float* xb = x + (size_t)b * CCH * NSP;

    float dxa[16] = {}, sxa[16] = {}, dya[16] = {}, sya[16] = {};

    for (int chk = pb; chk < 64; chk += 32) {       // 2 chunks of 256 px each
        const int f4 = chk * 64 + lane;             // float4 index in plane

        // ---- x: t_x for lane's 4 pixels, then per-i dot/sum (L1/L2 re-read) ----
        float4 t = make_float4(0.f, 0.f, 0.f, 0.f);
        #pragma unroll 8
        for (int j = 0; j < 64; ++j) {
            float wj = w1d[j];
            float4 v = ((const float4*)(xb + (size_t)j * NSP))[f4];
            t.x += wj * v.x; t.y += wj * v.y; t.z += wj * v.z; t.w += wj * v.w;
        }
        #pragma unroll
        for (int i = 0; i < 16; ++i) {
            float4 v = ((const float4*)(xb + (size_t)(ibase + i) * NSP))[f4];
            dxa[i] += v.x * t.x + v.y * t.y + v.z * t.z + v.w * t.w;
            sxa[i] += v.x + v.y + v.z + v.w;
        }

        // ---- y: same, from bf16 (YBF) or fp32 (fallback) ----
        float4 u = make_float4(0.f, 0.f, 0.f, 0.f);
        if (YBF) {
            const unsigned short* ybb = yb + (size_t)b * CCH * NSP;
            #pragma unroll 8
            for (int j = 0; j < 64; ++j) {
                float wj = w1d[j];
                ushort4 h = ((const ushort4*)(ybb + (size_t)j * NSP))[f4];
                u.x += wj * bfu(h.x); u.y += wj * bfu(h.y);
                u.z += wj * bfu(h.z); u.w += wj * bfu(h.w);
            }
            #pragma unroll
            for (int i = 0; i < 16; ++i) {
                ushort4 h = ((const ushort4*)(ybb + (size_t)(ibase + i) * NSP))[f4];
                float v0 = bfu(h.x), v1 = bfu(h.y), v2 = bfu(h.z), v3 = bfu(h.w);
                dya[i] += v0 * u.x + v1 * u.y + v2 * u.z + v3 * u.w;
                sya[i] += v0 + v1 + v2 + v3;
            }
        } else {
            const float* ybb = yf + (size_t)b * CCH * NSP;
            #pragma unroll 8
            for (int j = 0; j < 64; ++j) {
                float wj = w1d[j];
                float4 v = ((const float4*)(ybb + (size_t)j * NSP))[f4];
                u.x += wj * v.x; u.y += wj * v.y; u.z += wj * v.z; u.w += wj * v.w;
            }
            #pragma unroll
            for (int i = 0; i < 16; ++i) {
                float4 v = ((const float4*)(ybb + (size_t)(ibase + i) * NSP))[f4];
                dya[i] += v.x * u.x + v.y * u.y + v.z * u.z + v.w * u.w;
                sya[i] += v.x + v.y + v.z + v.w;
            }
        }
    }

    // per-wave lane reduction; lane 0 stores this block's partials
    #pragma unroll
    for (int i = 0; i < 16; ++i) {
        float a = dxa[i], d = dya[i], c = sxa[i], e = sya[i];
        #pragma unroll
        for (int off = 32; off > 0; off >>= 1) {
            a += __shfl_down(a, off); d += __shfl_down(d, off);
            c += __shfl_down(c, off); e += __shfl_down(e, off);
        }
        if (lane == 0) {
            const int idx = (pb * 32 + b) * 64 + ibase + i;
            dparts[idx]          = a;   // dot_x
            dparts[65536 + idx]  = d;   // dot_y
            dparts[131072 + idx] = c;   // S_x
            dparts[196608 + idx] = e;   // S_y
        }
    }
}

// ---------------- K3: sum partials; c, c_, softmax, att ---------------------------
__global__ __launch_bounds__(64) void att_kernel(
    const float* __restrict__ dparts, const float* __restrict__ w1d,
    const float* __restrict__ b1d, float* __restrict__ att)
{
    const int b = blockIdx.x;
    const int c = threadIdx.x;              // 0..63
    float dx = 0.f, dy = 0.f, sx = 0.f, sy = 0.f;
    for (int pb = 0; pb < 32; ++pb) {
        const int idx = (pb * 32 + b) * 64 + c;
        dx += dparts[idx];
        dy += dparts[65536 + idx];
        sx += dparts[131072 + idx];
        sy += dparts[196608 + idx];
    }
    const float w = w1d[c];
    float tsx = w * sx, tsy = w * sy;
    #pragma unroll
    for (int off = 32; off > 0; off >>= 1) {
        tsx += __shfl_xor(tsx, off);
        tsy += __shfl_xor(tsy, off);
    }
    const float inv_n  = 1.f / 16384.f;
    const float inv_n1 = 1.f / 16383.f;
    const float bb = b1d[0];
    float cxv = (dx - sx * inv_n * tsx) * inv_n1 + bb;
    float cyv = (dy - sy * inv_n * tsy) * inv_n1 + bb;
    float d = cyv - cxv;
    float m = d;
    #pragma unroll
    for (int off = 32; off > 0; off >>= 1) m = fmaxf(m, __shfl_xor(m, off));
    float e = __expf(d - m);
    float s = e;
    #pragma unroll
    for (int off = 32; off > 0; off >>= 1) s += __shfl_xor(s, off);
    float r = e / s;
    float a = cyv * (1.f + r);
    att[b * CCH + c] = 1.f / (1.f + __expf(-a));
}

// ---------------- K4: out = y * att -----------------------------------------------
template<int YBF>
__global__ __launch_bounds__(256) void scale_kernel(
    const unsigned short* __restrict__ yb, float* __restrict__ out,
    const float* __restrict__ att)
{
    const size_t total8 = (size_t)BATCH * CCH * NSP / 8;
    size_t i = (size_t)blockIdx.x * blockDim.x + threadIdx.x;
    const size_t stride = (size_t)gridDim.x * blockDim.x;
    if (YBF) {
        for (; i < total8; i += stride) {
            uint4 y = ((const uint4*)yb)[i];
            float a = att[(i * 8) >> 14];
            float4 o0 = make_float4(bflo(y.x) * a, bfhi(y.x) * a,
                                    bflo(y.y) * a, bfhi(y.y) * a);
            float4 o1 = make_float4(bflo(y.z) * a, bfhi(y.z) * a,
                                    bflo(y.w) * a, bfhi(y.w) * a);
            ((float4*)out)[2 * i]     = o0;
            ((float4*)out)[2 * i + 1] = o1;
        }
    } else {
        for (; i < total8; i += stride) {
            float a = att[(i * 8) >> 14];
            float4 v0 = ((const float4*)out)[2 * i];
            float4 v1 = ((const float4*)out)[2 * i + 1];
            v0.x *= a; v0.y *= a; v0.z *= a; v0.w *= a;
            v1.x *= a; v1.y *= a; v1.z *= a; v1.w *= a;
            ((float4*)out)[2 * i]     = v0;
            ((float4*)out)[2 * i + 1] = v1;
        }
    }
}

extern "C" void kernel_launch(void* const* d_in, const int* in_sizes, int n_in,
                              void* d_out, int out_size, void* d_ws, size_t ws_size,
                              hipStream_t stream) {
    const float* x   = (const float*)d_in[0];
    const float* w1d = (const float*)d_in[1];
    const float* b1d = (const float*)d_in[2];
    const float* wdw = (const float*)d_in[3];
    const float* bdw = (const float*)d_in[4];
    float* out = (float*)d_out;
    float* fw  = (float*)d_ws;

    // float workspace layout (tiny: 1 MB partials + att + zpad)
    float* dparts   = fw;                                   // 262144 floats
    float* att      = dparts + 262144;
    float* zpad     = att + 2048;                           // 64 floats
    float* fend     = zpad + 64;
    size_t fbytes   = (size_t)((char*)fend - (char*)fw);
    fbytes = (fbytes + 255) & ~(size_t)255;
    unsigned short* yb = (unsigned short*)((char*)d_ws + fbytes);
    const size_t yb_bytes = (size_t)BATCH * CCH * NSP * 2;  // 67.1 MB

    const bool ybf = (ws_size >= fbytes + yb_bytes);

    hipMemsetAsync(zpad, 0, 64 * sizeof(float), stream);

    if (ybf) {
        conv_kernel<1><<<dim3(4, BATCH, SPLIT), 256, 0, stream>>>(
            x, wdw, bdw, zpad, nullptr, yb);
        dot_kernel<1><<<1024, 256, 0, stream>>>(x, nullptr, yb, w1d, dparts);
        att_kernel<<<BATCH, 64, 0, stream>>>(dparts, w1d, b1d, att);
        scale_kernel<1><<<2048, 256, 0, stream>>>(yb, out, att);
    } else {
        conv_kernel<0><<<dim3(4, BATCH, SPLIT), 256, 0, stream>>>(
            x, wdw, bdw, zpad, out, nullptr);
        dot_kernel<0><<<1024, 256, 0, stream>>>(x, out, nullptr, w1d, dparts);
        att_kernel<<<BATCH, 64, 0, stream>>>(dparts, w1d, b1d, att);
        scale_kernel<0><<<2048, 256, 0, stream>>>(nullptr, out, att);
    }
}

// Round 10
// 188.937 us; speedup vs baseline: 1.1076x; 1.1076x over previous
//
#include <hip/hip_runtime.h>

#define NSP 16384   // H*W
#define CCH 64
#define BATCH 32
#define SPLIT 8
#define CPB (CCH / SPLIT)   // 8 channels per block

// LDS tile: full-width strip. 34 used quads/row (136 cols: 128 + 8 halo), pad to 40.
#define LW 160              // words per LDS row (40 quads)  [R8-proven config]
#define LH 40               // rows: 32 + 8 halo
#define LDSF (LW * LH)      // 6400 floats (25.6 KB per buffer)
#define NQ (LDSF / 4)       // 1600 quads
#define NISS 7              // ceil(1600/256); 7th issue only tid<64

__device__ __forceinline__ void gload_lds16(const float* g, float* l) {
    __builtin_amdgcn_global_load_lds(
        (const __attribute__((address_space(1))) void*)g,
        (__attribute__((address_space(3))) void*)l,
        16, 0, 0);
}

// quad-column swizzle: involution, spreads W=8 read pattern across bank groups
__device__ __forceinline__ int swq(int q) { return q ^ ((q >> 3) & 7); }

__device__ __forceinline__ unsigned short f2bf(float f) {   // RNE
    unsigned u = __float_as_uint(f);
    u += 0x7fffu + ((u >> 16) & 1u);
    return (unsigned short)(u >> 16);
}
__device__ __forceinline__ float bflo(unsigned u) { return __uint_as_float(u << 16); }
__device__ __forceinline__ float bfhi(unsigned u) { return __uint_as_float(u & 0xffff0000u); }

// ---------------- K1: depthwise 9x9 conv + inline t_x/t_y split-partials ----------
// R8's proven conv core (122.6 us). Additions (designed to be register-neutral):
//  - tya: accumulated in epilogue from yv (R5-proven free: 123 vs 122.6)
//  - txa: accumulated INLINE at ir==4/5 from v[] (x values live there anyway;
//         no cx capture array, no LDS re-read -- R7's poison avoided)
// Partials stored once per thread at kernel end (coalesced, no atomics).
template<int YBF>
__global__ __launch_bounds__(256, 3) void conv_kernel(
    const float* __restrict__ x, const float* __restrict__ wdw,
    const float* __restrict__ bdw, const float* __restrict__ w1d,
    const float* __restrict__ zpad,
    float* __restrict__ yf, unsigned short* __restrict__ yb,
    float* __restrict__ tx_parts, float* __restrict__ ty_parts)
{
    const int tile = blockIdx.x;            // 0..3: 32-row strips
    const int b    = blockIdx.y;
    const int sp   = blockIdx.z;            // channel split 0..7
    const int tile_ry = tile * 32;
    const int tid = threadIdx.x;
    const int tx = tid & 15, ty = tid >> 4;
    const int c0 = tx * 8, r0 = ty * 2;     // 8 cols x 2 rows per thread
    const int cbase = sp * CPB;

    __shared__ float bufs[2][LDSF];

    // staging geometry: LDS quad Q holds global quad swq(Q%40) of row Q/40
    int soff[NISS]; unsigned okm = 0;
    #pragma unroll
    for (int r = 0; r < NISS; ++r) {
        int q = tid + 256 * r;
        int lrow = q / 40, qcl = q - lrow * 40;
        int gq = swq(qcl);                  // global quad col (0 -> col -4)
        int gr = tile_ry - 4 + lrow;
        int gc = gq * 4 - 4;
        soff[r] = gr * 128 + gc;
        if (q < NQ && (unsigned)gr < 128u && gq >= 1 && gq <= 32) okm |= 1u << r;
    }

    // per-thread swizzled read base offsets (words), one per 16B column chunk
    int rb[4];
    #pragma unroll
    for (int j = 0; j < 4; ++j) rb[j] = r0 * LW + swq(2 * tx + j) * 4;

    const float* xb = x + (size_t)b * CCH * NSP;

#define STAGE(cc, dst) do {                                               \
        const float* plane_ = xb + (size_t)(cc) * NSP;                    \
        _Pragma("unroll")                                                 \
        for (int r_ = 0; r_ < NISS; ++r_) {                               \
            int q_ = tid + 256 * r_;                                      \
            if (q_ < NQ) {                                                \
                const float* g_ = ((okm >> r_) & 1u) ? plane_ + soff[r_]  \
                                                     : zpad;              \
                gload_lds16(g_, &(dst)[4 * q_]);                          \
            }                                                             \
        }                                                                 \
    } while (0)

    STAGE(cbase, bufs[0]);                  // prologue

    float txa[2][8] = {};
    float tya[2][8] = {};
    __syncthreads();                        // drains prologue vmcnt

    for (int k = 0; k < CPB; ++k) {
        const int c = cbase + k;
        if (k + 1 < CPB) STAGE(c + 1, bufs[(k + 1) & 1]);   // async prefetch

        const float* cb = bufs[k & 1];
        const float* wc = wdw + c * 81;     // uniform -> s_loads
        const float w1c = w1d[c];           // uniform -> s_load
        float acc[2][8] = {};
        #pragma unroll
        for (int ir = 0; ir < 10; ++ir) {
            float4 f0 = *(const float4*)(cb + rb[0] + ir * LW);
            float4 f1 = *(const float4*)(cb + rb[1] + ir * LW);
            float4 f2 = *(const float4*)(cb + rb[2] + ir * LW);
            float4 f3 = *(const float4*)(cb + rb[3] + ir * LW);
            float v[16] = {f0.x, f0.y, f0.z, f0.w, f1.x, f1.y, f1.z, f1.w,
                           f2.x, f2.y, f2.z, f2.w, f3.x, f3.y, f3.z, f3.w};
            // inline t_x accumulation: own-pixel x values pass through v[] here
            if (ir == 4) {
                #pragma unroll
                for (int q = 0; q < 8; ++q) txa[0][q] += w1c * v[q + 4];
            }
            if (ir == 5) {
                #pragma unroll
                for (int q = 0; q < 8; ++q) txa[1][q] += w1c * v[q + 4];
            }
            #pragma unroll
            for (int o = 0; o < 2; ++o) {
                int tv = ir - o;
                if (tv >= 0 && tv <= 8) {
                    #pragma unroll
                    for (int kx = 0; kx < 9; ++kx) {
                        float w = wc[tv * 9 + kx];
                        #pragma unroll
                        for (int q = 0; q < 8; ++q) acc[o][q] += w * v[kx + q];
                    }
                }
            }
        }

        const float bias = bdw[c];
        const size_t ybase = (size_t)(b * CCH + c) * NSP + (tile_ry + r0) * 128 + c0;
        #pragma unroll
        for (int o = 0; o < 2; ++o) {
            float yv[8];
            #pragma unroll
            for (int q = 0; q < 8; ++q) {
                yv[q] = acc[o][q] + bias;
                tya[o][q] += w1c * yv[q];
            }
            if (YBF) {
                uint4 s;
                s.x = (unsigned)f2bf(yv[0]) | ((unsigned)f2bf(yv[1]) << 16);
                s.y = (unsigned)f2bf(yv[2]) | ((unsigned)f2bf(yv[3]) << 16);
                s.z = (unsigned)f2bf(yv[4]) | ((unsigned)f2bf(yv[5]) << 16);
                s.w = (unsigned)f2bf(yv[6]) | ((unsigned)f2bf(yv[7]) << 16);
                *(uint4*)(yb + ybase + o * 128) = s;
            } else {
                *(float4*)(yf + ybase + o * 128) =
                    make_float4(yv[0], yv[1], yv[2], yv[3]);
                *(float4*)(yf + ybase + o * 128 + 4) =
                    make_float4(yv[4], yv[5], yv[6], yv[7]);
            }
        }
        __syncthreads();   // drains prefetch vmcnt + guards buffer reuse
    }
#undef STAGE

    // coalesced one-shot partial stores (summed by collapse; no atomics)
    const size_t tb = ((size_t)sp * BATCH + b) * NSP + (tile_ry + r0) * 128 + c0;
    float* txp = tx_parts + tb;
    float* typ = ty_parts + tb;
    #pragma unroll
    for (int o = 0; o < 2; ++o) {
        *(float4*)(txp + o * 128)     = make_float4(txa[o][0], txa[o][1], txa[o][2], txa[o][3]);
        *(float4*)(txp + o * 128 + 4) = make_float4(txa[o][4], txa[o][5], txa[o][6], txa[o][7]);
        *(float4*)(typ + o * 128)     = make_float4(tya[o][0], tya[o][1], tya[o][2], tya[o][3]);
        *(float4*)(typ + o * 128 + 4) = make_float4(tya[o][4], tya[o][5], tya[o][6], tya[o][7]);
    }
}

// ---------------- K1b: collapse split-partials into t_x, t_y ----------------------
// Each parts array: [SPLIT][BATCH][NSP] floats = 1M float4. i covers 2*128K out.
__global__ __launch_bounds__(256) void collapse_kernel(
    const float4* __restrict__ tx_parts, const float4* __restrict__ ty_parts,
    float4* __restrict__ t_x, float4* __restrict__ t_y)
{
    const int i = blockIdx.x * 256 + threadIdx.x;   // grid 1024 -> 262144
    const int tsel = i >> 17;                        // 0: t_x, 1: t_y
    const int j = i & 131071;                        // float4 idx within [32][4096]
    const float4* p = (tsel ? ty_parts : tx_parts) + j;
    float4 s = p[0];
    #pragma unroll
    for (int r = 1; r < SPLIT; ++r) {
        float4 a = p[(size_t)r * 131072];
        s.x += a.x; s.y += a.y; s.z += a.z; s.w += a.w;
    }
    (tsel ? t_y : t_x)[j] = s;
}

// ---------------- K2: dots + plane sums (single pass, materialized t) -------------
template<int YBF>
__global__ __launch_bounds__(256) void dot_kernel(
    const float* __restrict__ x, const float* __restrict__ yf,
    const unsigned short* __restrict__ yb,
    const float* __restrict__ t_x, const float* __restrict__ t_y,
    float* __restrict__ dot_x, float* __restrict__ dot_y,
    float* __restrict__ S_x, float* __restrict__ S_y)
{
    const int bc = blockIdx.x;              // 0..2047
    const int b  = bc >> 6;
    const int tid = threadIdx.x;
    const float4* xr  = (const float4*)(x   + (size_t)bc * NSP);
    const float4* txr = (const float4*)(t_x + (size_t)b * NSP);
    const float4* tyr = (const float4*)(t_y + (size_t)b * NSP);
    float dx = 0.f, dy = 0.f, sx = 0.f, sy = 0.f;
    if (YBF) {
        const uint4* yr = (const uint4*)(yb + (size_t)bc * NSP);
        for (int i = tid; i < NSP / 8; i += 256) {
            float4 x0 = xr[2 * i], x1 = xr[2 * i + 1];
            float4 t0 = txr[2 * i], t1 = txr[2 * i + 1];
            float4 u0 = tyr[2 * i], u1 = tyr[2 * i + 1];
            uint4 yv = yr[i];
            float y0 = bflo(yv.x), y1 = bfhi(yv.x), y2 = bflo(yv.y), y3 = bfhi(yv.y);
            float y4 = bflo(yv.z), y5 = bfhi(yv.z), y6 = bflo(yv.w), y7 = bfhi(yv.w);
            dx += x0.x * t0.x + x0.y * t0.y + x0.z * t0.z + x0.w * t0.w
                + x1.x * t1.x + x1.y * t1.y + x1.z * t1.z + x1.w * t1.w;
            sx += x0.x + x0.y + x0.z + x0.w + x1.x + x1.y + x1.z + x1.w;
            dy += y0 * u0.x + y1 * u0.y + y2 * u0.z + y3 * u0.w
                + y4 * u1.x + y5 * u1.y + y6 * u1.z + y7 * u1.w;
            sy += y0 + y1 + y2 + y3 + y4 + y5 + y6 + y7;
        }
    } else {
        const float4* yr = (const float4*)(yf + (size_t)bc * NSP);
        for (int i = tid; i < NSP / 4; i += 256) {
            float4 xv = xr[i], tv = txr[i];
            float4 yv = yr[i], uv = tyr[i];
            dx += xv.x * tv.x + xv.y * tv.y + xv.z * tv.z + xv.w * tv.w;
            sx += xv.x + xv.y + xv.z + xv.w;
            dy += yv.x * uv.x + yv.y * uv.y + yv.z * uv.z + yv.w * uv.w;
            sy += yv.x + yv.y + yv.z + yv.w;
        }
    }
    #pragma unroll
    for (int off = 32; off > 0; off >>= 1) {
        dx += __shfl_down(dx, off);
        dy += __shfl_down(dy, off);
        sx += __shfl_down(sx, off);
        sy += __shfl_down(sy, off);
    }
    __shared__ float red[16];
    const int wid = tid >> 6;
    if ((tid & 63) == 0) {
        red[wid * 4]     = dx; red[wid * 4 + 1] = dy;
        red[wid * 4 + 2] = sx; red[wid * 4 + 3] = sy;
    }
    __syncthreads();
    if (tid == 0) {
        dot_x[bc] = red[0] + red[4] + red[8]  + red[12];
        dot_y[bc] = red[1] + red[5] + red[9]  + red[13];
        S_x[bc]   = red[2] + red[6] + red[10] + red[14];
        S_y[bc]   = red[3] + red[7] + red[11] + red[15];
    }
}

// ---------------- K3: c, c_, softmax, att  (Tsum via w1d . S identity) ------------
__global__ __launch_bounds__(64) void att_kernel(
    const float* __restrict__ S_x, const float* __restrict__ S_y,
    const float* __restrict__ dot_x, const float* __restrict__ dot_y,
    const float* __restrict__ w1d, const float* __restrict__ b1d,
    float* __restrict__ att)
{
    const int b = blockIdx.x;
    const int c = threadIdx.x;              // 0..63
    const float sx = S_x[b * CCH + c];
    const float sy = S_y[b * CCH + c];
    const float w  = w1d[c];
    float tsx = w * sx, tsy = w * sy;
    #pragma unroll
    for (int off = 32; off > 0; off >>= 1) {
        tsx += __shfl_xor(tsx, off);
        tsy += __shfl_xor(tsy, off);
    }
    const float inv_n  = 1.f / 16384.f;
    const float inv_n1 = 1.f / 16383.f;
    const float bb = b1d[0];
    float cxv = (dot_x[b * CCH + c] - sx * inv_n * tsx) * inv_n1 + bb;
    float cyv = (dot_y[b * CCH + c] - sy * inv_n * tsy) * inv_n1 + bb;
    float d = cyv - cxv;
    float m = d;
    #pragma unroll
    for (int off = 32; off > 0; off >>= 1) m = fmaxf(m, __shfl_xor(m, off));
    float e = __expf(d - m);
    float s = e;
    #pragma unroll
    for (int off = 32; off > 0; off >>= 1) s += __shfl_xor(s, off);
    float r = e / s;
    float a = cyv * (1.f + r);
    att[b * CCH + c] = 1.f / (1.f + __expf(-a));
}

// ---------------- K4: out = y * att -----------------------------------------------
template<int YBF>
__global__ __launch_bounds__(256) void scale_kernel(
    const unsigned short* __restrict__ yb, float* __restrict__ out,
    const float* __restrict__ att)
{
    const size_t total8 = (size_t)BATCH * CCH * NSP / 8;
    size_t i = (size_t)blockIdx.x * blockDim.x + threadIdx.x;
    const size_t stride = (size_t)gridDim.x * blockDim.x;
    if (YBF) {
        for (; i < total8; i += stride) {
            uint4 y = ((const uint4*)yb)[i];
            float a = att[(i * 8) >> 14];
            float4 o0 = make_float4(bflo(y.x) * a, bfhi(y.x) * a,
                                    bflo(y.y) * a, bfhi(y.y) * a);
            float4 o1 = make_float4(bflo(y.z) * a, bfhi(y.z) * a,
                                    bflo(y.w) * a, bfhi(y.w) * a);
            ((float4*)out)[2 * i]     = o0;
            ((float4*)out)[2 * i + 1] = o1;
        }
    } else {
        for (; i < total8; i += stride) {
            float a = att[(i * 8) >> 14];
            float4 v0 = ((const float4*)out)[2 * i];
            float4 v1 = ((const float4*)out)[2 * i + 1];
            v0.x *= a; v0.y *= a; v0.z *= a; v0.w *= a;
            v1.x *= a; v1.y *= a; v1.z *= a; v1.w *= a;
            ((float4*)out)[2 * i]     = v0;
            ((float4*)out)[2 * i + 1] = v1;
        }
    }
}

extern "C" void kernel_launch(void* const* d_in, const int* in_sizes, int n_in,
                              void* d_out, int out_size, void* d_ws, size_t ws_size,
                              hipStream_t stream) {
    const float* x   = (const float*)d_in[0];
    const float* w1d = (const float*)d_in[1];
    const float* b1d = (const float*)d_in[2];
    const float* wdw = (const float*)d_in[3];
    const float* bdw = (const float*)d_in[4];
    float* out = (float*)d_out;
    float* fw  = (float*)d_ws;

    // float workspace layout (ybf fast path): ty_parts in ws, tx_parts aliases
    // d_out (dead until scale_kernel). Budget = 16.8 + 4.2 + ~0 + 67.1 = 88.2 MB,
    // the R0-proven envelope.
    const size_t PARTS = (size_t)SPLIT * BATCH * NSP;       // 4,194,304 floats
    float* ty_parts = fw;
    float* t_x      = ty_parts + PARTS;
    float* t_y      = t_x + (size_t)BATCH * NSP;
    float* S_x      = t_y + (size_t)BATCH * NSP;
    float* S_y      = S_x + 2048;
    float* dot_x    = S_y + 2048;
    float* dot_y    = dot_x + 2048;
    float* att      = dot_y + 2048;
    float* zpad     = att + 2048;                           // 64 floats
    float* fend     = zpad + 64;
    size_t fbytes   = (size_t)((char*)fend - (char*)fw);
    fbytes = (fbytes + 255) & ~(size_t)255;
    unsigned short* yb = (unsigned short*)((char*)d_ws + fbytes);
    const size_t yb_bytes = (size_t)BATCH * CCH * NSP * 2;  // 67.1 MB

    const bool ybf = (ws_size >= fbytes + yb_bytes);

    hipMemsetAsync(zpad, 0, 64 * sizeof(float), stream);

    if (ybf) {
        float* tx_parts = out;                              // alias d_out scratch
        conv_kernel<1><<<dim3(4, BATCH, SPLIT), 256, 0, stream>>>(
            x, wdw, bdw, w1d, zpad, nullptr, yb, tx_parts, ty_parts);
        collapse_kernel<<<1024, 256, 0, stream>>>(
            (const float4*)tx_parts, (const float4*)ty_parts,
            (float4*)t_x, (float4*)t_y);
        dot_kernel<1><<<2048, 256, 0, stream>>>(x, nullptr, yb, t_x, t_y,
                                                dot_x, dot_y, S_x, S_y);
        att_kernel<<<BATCH, 64, 0, stream>>>(S_x, S_y, dot_x, dot_y, w1d, b1d, att);
        scale_kernel<1><<<2048, 256, 0, stream>>>(yb, out, att);
    } else {
        // fallback: fp32 y in d_out; tx_parts placed where yb would have been
        float* tx_parts = (float*)((char*)d_ws + fbytes);
        conv_kernel<0><<<dim3(4, BATCH, SPLIT), 256, 0, stream>>>(
            x, wdw, bdw, w1d, zpad, out, nullptr, tx_parts, ty_parts);
        collapse_kernel<<<1024, 256, 0, stream>>>(
            (const float4*)tx_parts, (const float4*)ty_parts,
            (float4*)t_x, (float4*)t_y);
        dot_kernel<0><<<2048, 256, 0, stream>>>(x, out, nullptr, t_x, t_y,
                                                dot_x, dot_y, S_x, S_y);
        att_kernel<<<BATCH, 64, 0, stream>>>(S_x, S_y, dot_x, dot_y, w1d, b1d, att);
        scale_kernel<0><<<2048, 256, 0, stream>>>(nullptr, out, att);
    }
}